// Round 1
// 282.225 us; speedup vs baseline: 1.1395x; 1.1395x over previous
//
#include <hip/hip_runtime.h>

#define FDIM   128
#define HEADS  4
#define ALPHA  0.2f
#define DMASK  0x03FFFFFF     // low 26 bits = dst
#define PT     4096           // partition tile (edges per block)
#define NBMAX  1568           // max fine buckets supported by static LDS

typedef float v2f __attribute__((ext_vector_type(2)));

__device__ __forceinline__ float readlane_f(float v, int lane) {
  return __int_as_float(__builtin_amdgcn_readlane(__float_as_int(v), lane));
}

// ------- per-node scores + bf16-pack of x (+ fine-bucket histogram slice) ----
__global__ __launch_bounds__(256) void score_kernel(
    const float* __restrict__ x, const float* __restrict__ W,
    const float* __restrict__ a, float* __restrict__ s_src,
    float* __restrict__ s_dst, unsigned int* __restrict__ xb,
    const int* __restrict__ src, int* __restrict__ hist,
    int E, int HB, int n) {
  __shared__ int h[NBMAX];
  int lane = threadIdx.x & 63;
  int node = (blockIdx.x << 2) + (threadIdx.x >> 6);
  if (node < n) {
    const float2* x2 = (const float2*)x;
    const float2* W2 = (const float2*)W;
    const float2* a2 = (const float2*)a;
    float2 xv = x2[(size_t)node * 64 + lane];

    // bf16 pack (round-to-nearest-even)
    unsigned int u0 = __float_as_uint(xv.x);
    unsigned int u1 = __float_as_uint(xv.y);
    u0 += 0x7fffu + ((u0 >> 16) & 1u);
    u1 += 0x7fffu + ((u1 >> 16) & 1u);
    xb[(size_t)node * 64 + lane] = (u0 >> 16) | (u1 & 0xffff0000u);

#pragma unroll
    for (int k = 0; k < HEADS; k++) {
      float2 wv = W2[k * 64 + lane];
      float hx = xv.x * wv.x, hy = xv.y * wv.y;
      float2 as_ = a2[k * 128 + lane];        // a[k, 0:F]
      float2 ad_ = a2[k * 128 + 64 + lane];   // a[k, F:2F]
      float rs = hx * as_.x + hy * as_.y;
      float rd = hx * ad_.x + hy * ad_.y;
#pragma unroll
      for (int off = 32; off > 0; off >>= 1) {
        rs += __shfl_down(rs, off);
        rd += __shfl_down(rd, off);
      }
      if (lane == 0) {
        s_src[node * HEADS + k] = rs;
        s_dst[node * HEADS + k] = rd;
      }
    }
  }

  // histogram slice: blocks [0, HB) each cover 8192 edges with LDS pre-agg
  int b = blockIdx.x;
  if (b < HB) {
    int t = threadIdx.x;
    int NB = (n + 63) >> 6;
    for (int i = t; i < NB; i += 256) h[i] = 0;
    __syncthreads();
    int base = b * 8192;
#pragma unroll 4
    for (int j = 0; j < 32; j++) {
      int i = base + j * 256 + t;
      if (i < E) atomicAdd(&h[src[i] >> 6], 1);
    }
    __syncthreads();
    for (int i = t; i < NB; i += 256)
      if (h[i]) atomicAdd(&hist[i], h[i]);
  }
}

// ---------------- exclusive scan of NB (<=2048) bucket counts: 1 block -------
__global__ __launch_bounds__(256) void scan_kernel(const int* __restrict__ hist,
                                                   int* __restrict__ fine_ptr,
                                                   int* __restrict__ cursor,
                                                   int NB, int E) {
  __shared__ int lds[256];
  int t = threadIdx.x;
  int loc[8];
  int s = 0;
#pragma unroll
  for (int j = 0; j < 8; j++) {
    int idx = t * 8 + j;
    loc[j] = (idx < NB) ? hist[idx] : 0;
    s += loc[j];
  }
  lds[t] = s;
  __syncthreads();
  for (int off = 1; off < 256; off <<= 1) {
    int xv = (t >= off) ? lds[t - off] : 0;
    __syncthreads();
    lds[t] += xv;
    __syncthreads();
  }
  int run = lds[t] - s;   // exclusive prefix of this thread's segment
#pragma unroll
  for (int j = 0; j < 8; j++) {
    int idx = t * 8 + j;
    if (idx < NB) {
      fine_ptr[idx] = run;
      cursor[idx]   = run;
    }
    run += loc[j];
  }
  if (t == 0) fine_ptr[NB] = E;
}

// ---------------- partition: tile-sort 4096 edges by fine bucket in LDS ------
__global__ __launch_bounds__(256) void partition_kernel(
    const int* __restrict__ src, const int* __restrict__ dst,
    const float* __restrict__ adj, int* __restrict__ cursor,
    int2* __restrict__ ebuf, int E, int NB) {
  __shared__ int h[NBMAX];
  __shared__ int sc[NBMAX];
  __shared__ int bg[NBMAX];
  __shared__ unsigned short keyarr[PT];
  __shared__ int2 es[PT];
  __shared__ int lds[256];

  int t = threadIdx.x;
  int base = blockIdx.x * PT;
  for (int i = t; i < NB; i += 256) h[i] = 0;
  __syncthreads();

  int ssrc[16];
#pragma unroll
  for (int j = 0; j < 16; j++) {
    int i = base + j * 256 + t;
    ssrc[j] = (i < E) ? src[i] : -1;
    if (ssrc[j] >= 0) atomicAdd(&h[ssrc[j] >> 6], 1);
  }
  __syncthreads();

  int loc[8];
  int s = 0;
#pragma unroll
  for (int j = 0; j < 8; j++) {
    int idx = t * 8 + j;
    loc[j] = (idx < NB) ? h[idx] : 0;
    s += loc[j];
  }
  lds[t] = s;
  __syncthreads();
  for (int off = 1; off < 256; off <<= 1) {
    int xv = (t >= off) ? lds[t - off] : 0;
    __syncthreads();
    lds[t] += xv;
    __syncthreads();
  }
  int run = lds[t] - s;
#pragma unroll
  for (int j = 0; j < 8; j++) {
    int idx = t * 8 + j;
    if (idx < NB) sc[idx] = run;
    run += loc[j];
  }
  __syncthreads();

  for (int i = t; i < NB; i += 256)
    if (h[i]) bg[i] = atomicAdd(&cursor[i], h[i]);
  __syncthreads();

#pragma unroll
  for (int j = 0; j < 16; j++) {
    if (ssrc[j] >= 0) {
      int i = base + j * 256 + t;
      int k = ssrc[j] >> 6;
      int slot = atomicAdd(&sc[k], 1);
      int2 pk;
      pk.x = (int)(((unsigned)(ssrc[j] & 63) << 26) | (unsigned)dst[i]);
      pk.y = __float_as_int(adj[i]);
      es[slot] = pk;
      keyarr[slot] = (unsigned short)k;
    }
  }
  __syncthreads();

  int tc = E - base; if (tc > PT) tc = PT;
  for (int s2 = t; s2 < tc; s2 += 256) {
    int k = keyarr[s2];
    int rank = s2 - (sc[k] - h[k]);
    ebuf[bg[k] + rank] = es[s2];
  }
}

// ---------------- aggregate: one block per 32-node HALF-bucket ---------------
// Half-bucket split (grid = 2*NB): doubles block count (occupancy was
// grid+launch-bounds limited at 41%), halves the per-wave serial node chain
// (8 nodes/wave), and shrinks LDS 18.4KB -> ~9.6KB so 8 blocks/CU fit.
// Each block filters the parent bucket's edge range for its half (2 extra
// passes over ebuf, ~26MB total -- cheap vs the latency win).
// Epilogue: v_rcp + mul instead of 8 IEEE divides, __expf-1 instead of
// expm1f (epilogue was ~half the kernel's VALU instructions; error added
// ~1e-6 vs the 7.8e-3 bf16-dominated absmax budget).
// Padding invariant: slots >= cn carry pk={0,0} -> ev=0 and dst=0, so padded
// fmacs add exactly 0 (row 0 load is cached).
__global__ __launch_bounds__(256, 8) void aggregate_kernel(
    const unsigned int* __restrict__ xb, const float* __restrict__ W,
    const float* __restrict__ s_src, const float* __restrict__ s_dst,
    const int* __restrict__ fine_ptr, const int2* __restrict__ ebuf,
    float* __restrict__ out, int n) {
  __shared__ int2  es[1024];
  __shared__ float evbuf[4][64];
  __shared__ int   nbeg[33];
  __shared__ int   nrun[32];
  __shared__ int   h[32];

  int t = threadIdx.x, bb = blockIdx.x;
  int b0 = bb >> 1, half = bb & 1;     // parent 64-bucket, which half
  int lane = t & 63, wid = t >> 6;
  int beg = fine_ptr[b0];
  int L   = fine_ptr[b0 + 1] - beg;

  if (t < 32) h[t] = 0;
  __syncthreads();
  for (int i = t; i < L; i += 256) {
    int kk = (unsigned)ebuf[beg + i].x >> 26;
    if ((kk >> 5) == half) atomicAdd(&h[kk & 31], 1);
  }
  __syncthreads();
  if (t < 32) {   // lane 0..31 shfl inclusive scan of 32 counters
    int v = h[t];
#pragma unroll
    for (int off = 1; off < 32; off <<= 1) {
      int u = __shfl_up(v, off);
      if (lane >= off) v += u;
    }
    nbeg[t + 1] = v;
    nrun[t] = v - h[t];
    if (t == 0) nbeg[0] = 0;
  }
  __syncthreads();
  for (int i = t; i < L; i += 256) {
    int2 pk = ebuf[beg + i];
    int kk = (unsigned)pk.x >> 26;
    if ((kk >> 5) == half) {
      int slot = atomicAdd(&nrun[kk & 31], 1);
      es[slot] = pk;
    }
  }
  __syncthreads();

  int e = lane >> 2;                   // edge slot 0..15
  int k = lane & 3;                    // head

  for (int ni = 0; ni < 8; ni++) {
    int nl = wid * 8 + ni;
    int node = (b0 << 6) + (half << 5) + nl;
    if (node >= n) break;              // wave-uniform
    int eb = nbeg[nl], cnt = nbeg[nl + 1] - eb;
    float ssrc_k = s_src[node * HEADS + k];

    v2f acc0{0.f,0.f}, acc1{0.f,0.f}, acc2{0.f,0.f}, acc3{0.f,0.f};
    float rsum = 0.f;

    int c = 0;
    while (c < cnt) {
      int cn = cnt - c; if (cn > 16) cn = 16;
      int2 pk{0, 0};
      if (e < cn) pk = es[eb + c + e];
      int dv = pk.x & DMASK;

      // ---- issue ALL long-latency loads up front ----
      float sdv = s_dst[dv * HEADS + k];          // score gather (in flight)
      int dd[16];
#pragma unroll
      for (int j = 0; j < 16; j++)
        dd[j] = __builtin_amdgcn_readlane(pk.x, j * 4) & DMASK;
      unsigned int xw[16];
#pragma unroll
      for (int j = 0; j < 16; j++)
        xw[j] = xb[((unsigned)dd[j] << 6) + lane];  // 16 row gathers in flight

      // ---- ev phase (waits only on sdv; rows still flying) ----
      float s = ssrc_k + sdv;
      s = (s >= 0.f) ? s : ALPHA * s;
      float ev = __expf(s) * __int_as_float(pk.y);  // padded slots: adj=0 -> 0
      rsum += ev;
      evbuf[wid][lane] = ev;             // wave-private; in-order DS pipe

      // ---- fma drain ----
#pragma unroll
      for (int j = 0; j < 16; j++) {
        const float4 s4 = *(const float4*)&evbuf[wid][j * 4];
        v2f xv;
        xv.x = __uint_as_float(xw[j] << 16);
        xv.y = __uint_as_float(xw[j] & 0xffff0000u);
        acc0 += s4.x * xv;
        acc1 += s4.y * xv;
        acc2 += s4.z * xv;
        acc3 += s4.w * xv;
      }
      c += 16;
    }

    // rowsum per head (lane holds head lane&3 after the xor reduce)
    rsum += __shfl_xor(rsum, 4);
    rsum += __shfl_xor(rsum, 8);
    rsum += __shfl_xor(rsum, 16);
    rsum += __shfl_xor(rsum, 32);
    float rinv = __builtin_amdgcn_rcpf(rsum);   // 1 v_rcp vs 8 IEEE divides
    float r0 = readlane_f(rinv, 0), r1 = readlane_f(rinv, 1);
    float r2 = readlane_f(rinv, 2), r3 = readlane_f(rinv, 3);

    const float2* W2 = (const float2*)W;
    float2 o{0.f, 0.f};
    float hx, hy;
    {
      float2 wv = W2[0 * 64 + lane];
      hx = wv.x * acc0.x * r0; hy = wv.y * acc0.y * r0;
      o.x += (hx > 0.f) ? hx : (__expf(hx) - 1.f);
      o.y += (hy > 0.f) ? hy : (__expf(hy) - 1.f);
    }
    {
      float2 wv = W2[1 * 64 + lane];
      hx = wv.x * acc1.x * r1; hy = wv.y * acc1.y * r1;
      o.x += (hx > 0.f) ? hx : (__expf(hx) - 1.f);
      o.y += (hy > 0.f) ? hy : (__expf(hy) - 1.f);
    }
    {
      float2 wv = W2[2 * 64 + lane];
      hx = wv.x * acc2.x * r2; hy = wv.y * acc2.y * r2;
      o.x += (hx > 0.f) ? hx : (__expf(hx) - 1.f);
      o.y += (hy > 0.f) ? hy : (__expf(hy) - 1.f);
    }
    {
      float2 wv = W2[3 * 64 + lane];
      hx = wv.x * acc3.x * r3; hy = wv.y * acc3.y * r3;
      o.x += (hx > 0.f) ? hx : (__expf(hx) - 1.f);
      o.y += (hy > 0.f) ? hy : (__expf(hy) - 1.f);
    }
    o.x *= 0.25f; o.y *= 0.25f;
    ((float2*)out)[(size_t)node * 64 + lane] = o;
  }
}

extern "C" void kernel_launch(void* const* d_in, const int* in_sizes, int n_in,
                              void* d_out, int out_size, void* d_ws, size_t ws_size,
                              hipStream_t stream) {
  const float* x   = (const float*)d_in[0];
  const int*   edg = (const int*)d_in[1];
  const float* adj = (const float*)d_in[2];
  const float* W   = (const float*)d_in[3];
  const float* a   = (const float*)d_in[4];
  float* out = (float*)d_out;

  int E = in_sizes[2];
  int n = in_sizes[0] / FDIM;
  const int* src = edg;
  const int* dst = edg + E;
  int NB = (n + 63) >> 6;              // fine buckets of 64 nodes (<= NBMAX)
  int HB = (E + 8191) / 8192;          // histogram tiles

  auto align = [](size_t v) { return (v + 255) & ~(size_t)255; };
  char* ws = (char*)d_ws;
  int*   fine_ptr = (int*)ws;          ws += align((size_t)(NB + 1) * 4);
  int*   cursor   = (int*)ws;          ws += align((size_t)NB * 4);
  int*   hist     = (int*)ws;          ws += align((size_t)NB * 4);
  int2*  ebuf     = (int2*)ws;         ws += align((size_t)E * 8);
  float* s_src    = (float*)ws;        ws += align((size_t)n * HEADS * 4);
  float* s_dst    = (float*)ws;        ws += align((size_t)n * HEADS * 4);
  unsigned int* xb = (unsigned int*)ws; ws += align((size_t)n * 64 * 4);

  hipMemsetAsync(hist, 0, (size_t)NB * 4, stream);

  score_kernel<<<(n + 3) / 4, 256, 0, stream>>>(x, W, a, s_src, s_dst, xb,
                                                src, hist, E, HB, n);
  scan_kernel<<<1, 256, 0, stream>>>(hist, fine_ptr, cursor, NB, E);
  partition_kernel<<<(E + PT - 1) / PT, 256, 0, stream>>>(src, dst, adj, cursor,
                                                          ebuf, E, NB);
  aggregate_kernel<<<NB * 2, 256, 0, stream>>>(xb, W, s_src, s_dst, fine_ptr,
                                               ebuf, out, n);
}

// Round 2
// 280.202 us; speedup vs baseline: 1.1478x; 1.0072x over previous
//
#include <hip/hip_runtime.h>

#define FDIM   128
#define HEADS  4
#define ALPHA  0.2f
#define DMASK  0x03FFFFFF     // low 26 bits = dst
#define PT     4096           // partition tile (edges per block)
#define NBMAX  1568           // max fine buckets supported by static LDS

typedef float v2f __attribute__((ext_vector_type(2)));

__device__ __forceinline__ float readlane_f(float v, int lane) {
  return __int_as_float(__builtin_amdgcn_readlane(__float_as_int(v), lane));
}

// ------- per-node scores + bf16-pack of x (+ fine-bucket histogram slice) ----
// Reduction rewritten: multi-value butterfly. 8 series (4 heads x {src,dst})
// are split across lane groups via 3 pair-exchange steps (xor32 keep 4,
// xor16 keep 2, xor8 keep 1), then a 3-level xor{1,2,4} reduce. 10 shuffles
// per wave instead of 48 -- the DS pipe was the score bottleneck.
__global__ __launch_bounds__(256) void score_kernel(
    const float* __restrict__ x, const float* __restrict__ W,
    const float* __restrict__ a, float* __restrict__ s_src,
    float* __restrict__ s_dst, unsigned int* __restrict__ xb,
    const int* __restrict__ src, int* __restrict__ hist,
    int E, int HB, int n) {
  __shared__ int h[NBMAX];
  int lane = threadIdx.x & 63;
  int node = (blockIdx.x << 2) + (threadIdx.x >> 6);
  if (node < n) {
    const float2* x2 = (const float2*)x;
    const float2* W2 = (const float2*)W;
    const float2* a2 = (const float2*)a;
    float2 xv = x2[(size_t)node * 64 + lane];

    // bf16 pack (round-to-nearest-even)
    unsigned int u0 = __float_as_uint(xv.x);
    unsigned int u1 = __float_as_uint(xv.y);
    u0 += 0x7fffu + ((u0 >> 16) & 1u);
    u1 += 0x7fffu + ((u1 >> 16) & 1u);
    xb[(size_t)node * 64 + lane] = (u0 >> 16) | (u1 & 0xffff0000u);

    float p[8];   // p[0..3] = rs per head, p[4..7] = rd per head
#pragma unroll
    for (int k = 0; k < HEADS; k++) {
      float2 wv = W2[k * 64 + lane];
      float hx = xv.x * wv.x, hy = xv.y * wv.y;
      float2 as_ = a2[k * 128 + lane];        // a[k, 0:F]
      float2 ad_ = a2[k * 128 + 64 + lane];   // a[k, F:2F]
      p[k]         = hx * as_.x + hy * as_.y;
      p[4 + k]     = hx * ad_.x + hy * ad_.y;
    }

    // step A: xor 32 -- keep 4 series chosen by lane bit5
    bool h5 = (lane & 32) != 0;
    float q[4];
#pragma unroll
    for (int k = 0; k < 4; k++) {
      float send = h5 ? p[k] : p[4 + k];      // the series we give away
      float got = __shfl_xor(send, 32);       // partner sends what we keep
      q[k] = (h5 ? p[4 + k] : p[k]) + got;
    }
    // step B: xor 16 -- keep 2 chosen by bit4
    bool h4 = (lane & 16) != 0;
    float r[2];
#pragma unroll
    for (int j = 0; j < 2; j++) {
      float send = h4 ? q[j] : q[2 + j];
      float got = __shfl_xor(send, 16);
      r[j] = (h4 ? q[2 + j] : q[j]) + got;
    }
    // step C: xor 8 -- keep 1 chosen by bit3
    bool h3 = (lane & 8) != 0;
    float send = h3 ? r[0] : r[1];
    float got = __shfl_xor(send, 8);
    float v = (h3 ? r[1] : r[0]) + got;
    // step D: reduce the remaining 8-lane groups (bits 0..2)
    v += __shfl_xor(v, 1);
    v += __shfl_xor(v, 2);
    v += __shfl_xor(v, 4);
    // lane L holds series (L>>3): 0..3 = s_src heads, 4..7 = s_dst heads
    if ((lane & 7) == 0) {
      int s = lane >> 3;
      if (s < 4) s_src[node * HEADS + s] = v;
      else       s_dst[node * HEADS + (s - 4)] = v;
    }
  }

  // histogram slice: blocks [0, HB) each cover 8192 edges with LDS pre-agg
  int b = blockIdx.x;
  if (b < HB) {
    int t = threadIdx.x;
    int NB = (n + 63) >> 6;
    for (int i = t; i < NB; i += 256) h[i] = 0;
    __syncthreads();
    int base = b * 8192;
#pragma unroll 4
    for (int j = 0; j < 32; j++) {
      int i = base + j * 256 + t;
      if (i < E) atomicAdd(&h[src[i] >> 6], 1);
    }
    __syncthreads();
    for (int i = t; i < NB; i += 256)
      if (h[i]) atomicAdd(&hist[i], h[i]);
  }
}

// ---------------- exclusive scan of NB (<=2048) bucket counts: 1 block -------
__global__ __launch_bounds__(256) void scan_kernel(const int* __restrict__ hist,
                                                   int* __restrict__ fine_ptr,
                                                   int* __restrict__ cursor,
                                                   int NB, int E) {
  __shared__ int lds[256];
  int t = threadIdx.x;
  int loc[8];
  int s = 0;
#pragma unroll
  for (int j = 0; j < 8; j++) {
    int idx = t * 8 + j;
    loc[j] = (idx < NB) ? hist[idx] : 0;
    s += loc[j];
  }
  lds[t] = s;
  __syncthreads();
  for (int off = 1; off < 256; off <<= 1) {
    int xv = (t >= off) ? lds[t - off] : 0;
    __syncthreads();
    lds[t] += xv;
    __syncthreads();
  }
  int run = lds[t] - s;   // exclusive prefix of this thread's segment
#pragma unroll
  for (int j = 0; j < 8; j++) {
    int idx = t * 8 + j;
    if (idx < NB) {
      fine_ptr[idx] = run;
      cursor[idx]   = run;
    }
    run += loc[j];
  }
  if (t == 0) fine_ptr[NB] = E;
}

// ---------------- partition: tile-sort 4096 edges by fine bucket in LDS ------
__global__ __launch_bounds__(256) void partition_kernel(
    const int* __restrict__ src, const int* __restrict__ dst,
    const float* __restrict__ adj, int* __restrict__ cursor,
    int2* __restrict__ ebuf, int E, int NB) {
  __shared__ int h[NBMAX];
  __shared__ int sc[NBMAX];
  __shared__ int bg[NBMAX];
  __shared__ unsigned short keyarr[PT];
  __shared__ int2 es[PT];
  __shared__ int lds[256];

  int t = threadIdx.x;
  int base = blockIdx.x * PT;
  for (int i = t; i < NB; i += 256) h[i] = 0;
  __syncthreads();

  int ssrc[16];
#pragma unroll
  for (int j = 0; j < 16; j++) {
    int i = base + j * 256 + t;
    ssrc[j] = (i < E) ? src[i] : -1;
    if (ssrc[j] >= 0) atomicAdd(&h[ssrc[j] >> 6], 1);
  }
  __syncthreads();

  int loc[8];
  int s = 0;
#pragma unroll
  for (int j = 0; j < 8; j++) {
    int idx = t * 8 + j;
    loc[j] = (idx < NB) ? h[idx] : 0;
    s += loc[j];
  }
  lds[t] = s;
  __syncthreads();
  for (int off = 1; off < 256; off <<= 1) {
    int xv = (t >= off) ? lds[t - off] : 0;
    __syncthreads();
    lds[t] += xv;
    __syncthreads();
  }
  int run = lds[t] - s;
#pragma unroll
  for (int j = 0; j < 8; j++) {
    int idx = t * 8 + j;
    if (idx < NB) sc[idx] = run;
    run += loc[j];
  }
  __syncthreads();

  for (int i = t; i < NB; i += 256)
    if (h[i]) bg[i] = atomicAdd(&cursor[i], h[i]);
  __syncthreads();

#pragma unroll
  for (int j = 0; j < 16; j++) {
    if (ssrc[j] >= 0) {
      int i = base + j * 256 + t;
      int k = ssrc[j] >> 6;
      int slot = atomicAdd(&sc[k], 1);
      int2 pk;
      pk.x = (int)(((unsigned)(ssrc[j] & 63) << 26) | (unsigned)dst[i]);
      pk.y = __float_as_int(adj[i]);
      es[slot] = pk;
      keyarr[slot] = (unsigned short)k;
    }
  }
  __syncthreads();

  int tc = E - base; if (tc > PT) tc = PT;
  for (int s2 = t; s2 < tc; s2 += 256) {
    int k = keyarr[s2];
    int rank = s2 - (sc[k] - h[k]);
    ebuf[bg[k] + rank] = es[s2];
  }
}

// ---------------- aggregate: one block per 16-node QUARTER-bucket ------------
// Quarter-bucket split (grid = 4*NB ~= 24.4 blocks/CU): smooths the 8-blocks/
// CU scheduling rounds that left occupancy at 59% with half-buckets (12.2
// blocks/CU -> rounds of 8 then ~4). LDS ~5.5KB. Cost: the parent bucket's
// edge range is filter-scanned by 4 blocks instead of 2 (+~13MB fetch, ~2us).
// es[512] keeps 2x headroom over the 256-edge mean per 16-node group.
// Padding invariant: slots >= cn carry pk={0,0} -> ev=0 and dst=0, so padded
// fmacs add exactly 0 (row 0 load is cached).
__global__ __launch_bounds__(256, 8) void aggregate_kernel(
    const unsigned int* __restrict__ xb, const float* __restrict__ W,
    const float* __restrict__ s_src, const float* __restrict__ s_dst,
    const int* __restrict__ fine_ptr, const int2* __restrict__ ebuf,
    float* __restrict__ out, int n) {
  __shared__ int2  es[512];
  __shared__ float evbuf[4][64];
  __shared__ int   nbeg[17];
  __shared__ int   nrun[16];
  __shared__ int   h[16];

  int t = threadIdx.x, bb = blockIdx.x;
  int b0 = bb >> 2, qtr = bb & 3;      // parent 64-bucket, which quarter
  int lane = t & 63, wid = t >> 6;
  int beg = fine_ptr[b0];
  int L   = fine_ptr[b0 + 1] - beg;

  if (t < 16) h[t] = 0;
  __syncthreads();
  for (int i = t; i < L; i += 256) {
    int kk = (unsigned)ebuf[beg + i].x >> 26;
    if ((kk >> 4) == qtr) atomicAdd(&h[kk & 15], 1);
  }
  __syncthreads();
  if (t < 16) {   // lane 0..15 shfl inclusive scan of 16 counters
    int v = h[t];
#pragma unroll
    for (int off = 1; off < 16; off <<= 1) {
      int u = __shfl_up(v, off);
      if (lane >= off) v += u;
    }
    nbeg[t + 1] = v;
    nrun[t] = v - h[t];
    if (t == 0) nbeg[0] = 0;
  }
  __syncthreads();
  for (int i = t; i < L; i += 256) {
    int2 pk = ebuf[beg + i];
    int kk = (unsigned)pk.x >> 26;
    if ((kk >> 4) == qtr) {
      int slot = atomicAdd(&nrun[kk & 15], 1);
      es[slot] = pk;
    }
  }
  __syncthreads();

  int e = lane >> 2;                   // edge slot 0..15
  int k = lane & 3;                    // head

  for (int ni = 0; ni < 4; ni++) {
    int nl = wid * 4 + ni;
    int node = (b0 << 6) + (qtr << 4) + nl;
    if (node >= n) break;              // wave-uniform
    int eb = nbeg[nl], cnt = nbeg[nl + 1] - eb;
    float ssrc_k = s_src[node * HEADS + k];

    v2f acc0{0.f,0.f}, acc1{0.f,0.f}, acc2{0.f,0.f}, acc3{0.f,0.f};
    float rsum = 0.f;

    int c = 0;
    while (c < cnt) {
      int cn = cnt - c; if (cn > 16) cn = 16;
      int2 pk{0, 0};
      if (e < cn) pk = es[eb + c + e];
      int dv = pk.x & DMASK;

      // ---- issue ALL long-latency loads up front ----
      float sdv = s_dst[dv * HEADS + k];          // score gather (in flight)
      int dd[16];
#pragma unroll
      for (int j = 0; j < 16; j++)
        dd[j] = __builtin_amdgcn_readlane(pk.x, j * 4) & DMASK;
      unsigned int xw[16];
#pragma unroll
      for (int j = 0; j < 16; j++)
        xw[j] = xb[((unsigned)dd[j] << 6) + lane];  // 16 row gathers in flight

      // ---- ev phase (waits only on sdv; rows still flying) ----
      float s = ssrc_k + sdv;
      s = (s >= 0.f) ? s : ALPHA * s;
      float ev = __expf(s) * __int_as_float(pk.y);  // padded slots: adj=0 -> 0
      rsum += ev;
      evbuf[wid][lane] = ev;             // wave-private; in-order DS pipe

      // ---- fma drain ----
#pragma unroll
      for (int j = 0; j < 16; j++) {
        const float4 s4 = *(const float4*)&evbuf[wid][j * 4];
        v2f xv;
        xv.x = __uint_as_float(xw[j] << 16);
        xv.y = __uint_as_float(xw[j] & 0xffff0000u);
        acc0 += s4.x * xv;
        acc1 += s4.y * xv;
        acc2 += s4.z * xv;
        acc3 += s4.w * xv;
      }
      c += 16;
    }

    // rowsum per head (lane holds head lane&3 after the xor reduce)
    rsum += __shfl_xor(rsum, 4);
    rsum += __shfl_xor(rsum, 8);
    rsum += __shfl_xor(rsum, 16);
    rsum += __shfl_xor(rsum, 32);
    float rinv = __builtin_amdgcn_rcpf(rsum);   // 1 v_rcp vs 8 IEEE divides
    float r0 = readlane_f(rinv, 0), r1 = readlane_f(rinv, 1);
    float r2 = readlane_f(rinv, 2), r3 = readlane_f(rinv, 3);

    const float2* W2 = (const float2*)W;
    float2 o{0.f, 0.f};
    float hx, hy;
    {
      float2 wv = W2[0 * 64 + lane];
      hx = wv.x * acc0.x * r0; hy = wv.y * acc0.y * r0;
      o.x += (hx > 0.f) ? hx : (__expf(hx) - 1.f);
      o.y += (hy > 0.f) ? hy : (__expf(hy) - 1.f);
    }
    {
      float2 wv = W2[1 * 64 + lane];
      hx = wv.x * acc1.x * r1; hy = wv.y * acc1.y * r1;
      o.x += (hx > 0.f) ? hx : (__expf(hx) - 1.f);
      o.y += (hy > 0.f) ? hy : (__expf(hy) - 1.f);
    }
    {
      float2 wv = W2[2 * 64 + lane];
      hx = wv.x * acc2.x * r2; hy = wv.y * acc2.y * r2;
      o.x += (hx > 0.f) ? hx : (__expf(hx) - 1.f);
      o.y += (hy > 0.f) ? hy : (__expf(hy) - 1.f);
    }
    {
      float2 wv = W2[3 * 64 + lane];
      hx = wv.x * acc3.x * r3; hy = wv.y * acc3.y * r3;
      o.x += (hx > 0.f) ? hx : (__expf(hx) - 1.f);
      o.y += (hy > 0.f) ? hy : (__expf(hy) - 1.f);
    }
    o.x *= 0.25f; o.y *= 0.25f;
    ((float2*)out)[(size_t)node * 64 + lane] = o;
  }
}

extern "C" void kernel_launch(void* const* d_in, const int* in_sizes, int n_in,
                              void* d_out, int out_size, void* d_ws, size_t ws_size,
                              hipStream_t stream) {
  const float* x   = (const float*)d_in[0];
  const int*   edg = (const int*)d_in[1];
  const float* adj = (const float*)d_in[2];
  const float* W   = (const float*)d_in[3];
  const float* a   = (const float*)d_in[4];
  float* out = (float*)d_out;

  int E = in_sizes[2];
  int n = in_sizes[0] / FDIM;
  const int* src = edg;
  const int* dst = edg + E;
  int NB = (n + 63) >> 6;              // fine buckets of 64 nodes (<= NBMAX)
  int HB = (E + 8191) / 8192;          // histogram tiles

  auto align = [](size_t v) { return (v + 255) & ~(size_t)255; };
  char* ws = (char*)d_ws;
  int*   fine_ptr = (int*)ws;          ws += align((size_t)(NB + 1) * 4);
  int*   cursor   = (int*)ws;          ws += align((size_t)NB * 4);
  int*   hist     = (int*)ws;          ws += align((size_t)NB * 4);
  int2*  ebuf     = (int2*)ws;         ws += align((size_t)E * 8);
  float* s_src    = (float*)ws;        ws += align((size_t)n * HEADS * 4);
  float* s_dst    = (float*)ws;        ws += align((size_t)n * HEADS * 4);
  unsigned int* xb = (unsigned int*)ws; ws += align((size_t)n * 64 * 4);

  hipMemsetAsync(hist, 0, (size_t)NB * 4, stream);

  score_kernel<<<(n + 3) / 4, 256, 0, stream>>>(x, W, a, s_src, s_dst, xb,
                                                src, hist, E, HB, n);
  scan_kernel<<<1, 256, 0, stream>>>(hist, fine_ptr, cursor, NB, E);
  partition_kernel<<<(E + PT - 1) / PT, 256, 0, stream>>>(src, dst, adj, cursor,
                                                          ebuf, E, NB);
  aggregate_kernel<<<NB * 4, 256, 0, stream>>>(xb, W, s_src, s_dst, fine_ptr,
                                               ebuf, out, n);
}